// Round 11
// baseline (434.384 us; speedup 1.0000x reference)
//
#include <hip/hip_runtime.h>
#include <hip/hip_bf16.h>

#define HIDDEN 1024
#define NHEAD 16
#define HDIM 64
#define VOCAB 32000
#define SEQLEN 1024
#define EMBED 512
#define BATCH 4
#define ROWS (BATCH*SEQLEN)   // 4096

typedef __bf16 bf16x8 __attribute__((ext_vector_type(8)));
typedef float f32x4 __attribute__((ext_vector_type(4)));
typedef unsigned short u16;

#define MFMA(a_, b_, c_) __builtin_amdgcn_mfma_f32_16x16x32_bf16(a_, b_, c_, 0, 0, 0)

#define VMCNT6 asm volatile("s_waitcnt vmcnt(6)" ::: "memory")
#define VMCNT4 asm volatile("s_waitcnt vmcnt(4)" ::: "memory")
#define VMCNT0 asm volatile("s_waitcnt vmcnt(0)" ::: "memory")
#define LGKM0  asm volatile("s_waitcnt lgkmcnt(0)" ::: "memory")
#define CFENCE asm volatile("" ::: "memory")
#define SBAR   __builtin_amdgcn_s_barrier()
#define SCHEDB __builtin_amdgcn_sched_barrier(0)

__device__ __forceinline__ u16 f2bf(float f) {
  unsigned u = __builtin_bit_cast(unsigned, f);
  u = u + 0x7FFFu + ((u >> 16) & 1u);
  return (u16)(u >> 16);
}
__device__ __forceinline__ float bf2f(u16 s) {
  unsigned u = (unsigned)s << 16;
  return __builtin_bit_cast(float, u);
}

// async global->LDS, 16B/lane; LDS dest = wave-uniform base + lane*16
#define GLDS(g_, l_) __builtin_amdgcn_global_load_lds( \
    (const __attribute__((address_space(1))) void*)(g_), \
    (__attribute__((address_space(3))) void*)(l_), 16, 0, 0)

// ---------------- fused prep: 8 small weight cvts + W_lm cvt + embedding
struct Prep {
  const float* src[8]; u16* dst[8];
  const float* wlm; u16* wlm_dst;
  const int* ids; const float* wword; const float* wpos; u16* h0b;
};
__global__ void prep_kernel(Prep pp) {
  int b = blockIdx.x;
  if (b < 13312) {
    int seg, off;
    if (b < 4096)        { seg = b >> 10; off = b & 1023; }
    else if (b < 8192)   { seg = 4; off = b - 4096; }
    else if (b < 12288)  { seg = 5; off = b - 8192; }
    else if (b < 12800)  { seg = 6; off = b - 12288; }
    else                 { seg = 7; off = b - 12800; }
    size_t i = ((size_t)off * 256 + threadIdx.x) * 4;
    float4 v = *(const float4*)(pp.src[seg] + i);
    unsigned a = f2bf(v.x) | ((unsigned)f2bf(v.y) << 16);
    unsigned d = f2bf(v.z) | ((unsigned)f2bf(v.w) << 16);
    *(uint2*)(pp.dst[seg] + i) = make_uint2(a, d);
  } else if (b < 29312) {
    if (!pp.wlm_dst) return;
    int off = b - 13312;
    size_t i = ((size_t)off * 256 + threadIdx.x) * 4;
    float4 v = *(const float4*)(pp.wlm + i);
    unsigned a = f2bf(v.x) | ((unsigned)f2bf(v.y) << 16);
    unsigned d = f2bf(v.z) | ((unsigned)f2bf(v.w) << 16);
    *(uint2*)(pp.wlm_dst + i) = make_uint2(a, d);
  } else {
    int off = b - 29312;
    int row = off * 2 + (threadIdx.x >> 7);
    int e = (threadIdx.x & 127) * 4;
    int s = row & (SEQLEN - 1);
    int id = pp.ids[row];
    float4 a = *(const float4*)(pp.wword + (size_t)id * EMBED + e);
    float4 c = *(const float4*)(pp.wpos + (size_t)s * EMBED + e);
    unsigned lo = f2bf(a.x + c.x) | ((unsigned)f2bf(a.y + c.y) << 16);
    unsigned hi = f2bf(a.z + c.z) | ((unsigned)f2bf(a.w + c.w) << 16);
    *(uint2*)(pp.h0b + (size_t)row * EMBED + e) = make_uint2(lo, hi);
  }
}

// ======================================================================
// 128xBN GEMM, 4 waves, dbuf LDS, rotation-swizzled, counted-vmcnt dual-barrier.
// (round-10 verified version, unchanged)
template<int EPI, bool WF32, bool WB16, bool BF32, bool SWZ, bool NT, int BN>
__global__ __launch_bounds__(256, 2) void gemm128(
    const u16* __restrict__ A, const u16* __restrict__ Bb,
    const float* __restrict__ Bf,
    float* __restrict__ C, u16* __restrict__ Cb,
    const u16* __restrict__ R, int K, int ldc)
{
  constexpr int NF  = BN / 32;
  constexpr int BCH = BN / 32;
  __shared__ __align__(16) u16 smem[16384 + 2 * BN * 64];
  u16* As0 = &smem[0];
  u16* As1 = &smem[8192];
  u16* Bs0 = &smem[16384];
  u16* Bs1 = &smem[16384 + BN * 64];

  int tid = threadIdx.x;
  int lane = tid & 63, wave = tid >> 6;
  int wr = wave >> 1, wc = wave & 1;
  int cl = lane & 15, gp = (lane >> 4) & 3;

  int bx = blockIdx.x, by = blockIdx.y;
  if (SWZ) {
    int nwg = gridDim.x * gridDim.y;
    int flat = by * gridDim.x + bx;
    int cpx = nwg >> 3;
    int swz = (flat & 7) * cpx + (flat >> 3);
    bx = swz % gridDim.x; by = swz / gridDim.x;
  }
  int m0 = bx * 128, n0 = by * BN;

  int srow8 = lane >> 3;
  int scol = (((lane & 7) - srow8) & 7) * 8;
  int pos0 = ((gp + cl) & 7) * 8;
  int pos1 = ((gp + cl + 4) & 7) * 8;

  f32x4 acc[4][NF] = {};
  int nk = K >> 6;

  #pragma unroll
  for (int i = 0; i < 4; ++i) {
    int c = i * 4 + wave;
    GLDS(A + (size_t)(m0 + c * 8 + srow8) * K + scol, As0 + c * 512);
  }
  if (!BF32) {
    #pragma unroll
    for (int i = 0; i < BCH; ++i) {
      int c = i * 4 + wave;
      GLDS(Bb + (size_t)(n0 + c * 8 + srow8) * K + scol, Bs0 + c * 512);
    }
  } else {
    #pragma unroll
    for (int it = 0; it < BN / 32; ++it) {
      int idx = it * 256 + tid;
      int row = idx >> 3, p = idx & 7;
      int gc = (p - row) & 7;
      const float* src = Bf + (size_t)(n0 + row) * K + gc * 8;
      float4 v0 = *(const float4*)src, v1 = *(const float4*)(src + 4);
      union { bf16x8 v; u16 s[8]; } u;
      u.s[0]=f2bf(v0.x); u.s[1]=f2bf(v0.y); u.s[2]=f2bf(v0.z); u.s[3]=f2bf(v0.w);
      u.s[4]=f2bf(v1.x); u.s[5]=f2bf(v1.y); u.s[6]=f2bf(v1.z); u.s[7]=f2bf(v1.w);
      *(bf16x8*)&Bs0[row * 64 + p * 8] = u.v;
    }
  }

  for (int kt = 0; kt < nk; ++kt) {
    int buf = kt & 1;
    u16* Asb = buf ? As1 : As0;
    u16* Bsb = buf ? Bs1 : Bs0;
    u16* Asn = buf ? As0 : As1;
    u16* Bsn = buf ? Bs0 : Bs1;
    int kb = (kt + 1) << 6;
    bool more = kt + 1 < nk;

    if (more) {
      #pragma unroll
      for (int i = 0; i < 4; ++i) {
        int c = i * 4 + wave;
        GLDS(A + (size_t)(m0 + c * 8 + srow8) * K + kb + scol, Asn + c * 512);
      }
    }
    if (BF32) { VMCNT0; } else if (more) { VMCNT4; } else { VMCNT0; }
    SCHEDB;
    SBAR;
    CFENCE; SCHEDB;

    bf16x8 af[4][2], bfv[NF][2];
    #pragma unroll
    for (int n = 0; n < NF; ++n) {
      int r = (wc * (BN / 2) + n * 16 + cl) * 64;
      bfv[n][0] = *(const bf16x8*)&Bsb[r + pos0];
      bfv[n][1] = *(const bf16x8*)&Bsb[r + pos1];
    }
    #pragma unroll
    for (int m = 0; m < 4; ++m) {
      int r = (wr * 64 + m * 16 + cl) * 64;
      af[m][0] = *(const bf16x8*)&Asb[r + pos0];
      af[m][1] = *(const bf16x8*)&Asb[r + pos1];
    }

    __builtin_amdgcn_s_setprio(1);
    #pragma unroll
    for (int m = 0; m < 2; ++m)
      #pragma unroll
      for (int n = 0; n < NF; ++n)
        #pragma unroll
        for (int ks = 0; ks < 2; ++ks)
          acc[m][n] = MFMA(af[m][ks], bfv[n][ks], acc[m][n]);
    __builtin_amdgcn_s_setprio(0);

    if (more) {
      if (!BF32) {
        #pragma unroll
        for (int i = 0; i < BCH; ++i) {
          int c = i * 4 + wave;
          GLDS(Bb + (size_t)(n0 + c * 8 + srow8) * K + kb + scol, Bsn + c * 512);
        }
      } else {
        #pragma unroll
        for (int it = 0; it < BN / 32; ++it) {
          int idx = it * 256 + tid;
          int row = idx >> 3, p = idx & 7;
          int gc = (p - row) & 7;
          const float* src = Bf + (size_t)(n0 + row) * K + kb + gc * 8;
          float4 v0 = *(const float4*)src, v1 = *(const float4*)(src + 4);
          union { bf16x8 v; u16 s[8]; } u;
          u.s[0]=f2bf(v0.x); u.s[1]=f2bf(v0.y); u.s[2]=f2bf(v0.z); u.s[3]=f2bf(v0.w);
          u.s[4]=f2bf(v1.x); u.s[5]=f2bf(v1.y); u.s[6]=f2bf(v1.z); u.s[7]=f2bf(v1.w);
          *(bf16x8*)&Bsn[row * 64 + p * 8] = u.v;
        }
      }
    }

    __builtin_amdgcn_s_setprio(1);
    #pragma unroll
    for (int n = 0; n < NF; ++n)
      #pragma unroll
      for (int ks = 0; ks < 2; ++ks)
        acc[2][n] = MFMA(af[2][ks], bfv[n][ks], acc[2][n]);
    __builtin_amdgcn_s_setprio(0);

    LGKM0;
    SCHEDB;
    SBAR;
    CFENCE; SCHEDB;

    __builtin_amdgcn_s_setprio(1);
    #pragma unroll
    for (int n = 0; n < NF; ++n)
      #pragma unroll
      for (int ks = 0; ks < 2; ++ks)
        acc[3][n] = MFMA(af[3][ks], bfv[n][ks], acc[3][n]);
    __builtin_amdgcn_s_setprio(0);
  }

  if constexpr (WF32 && !WB16 && BN == 128) {
    float* Cst = (float*)&smem[0];
    __syncthreads();
    #pragma unroll
    for (int g = 0; g < 2; ++g) {
      if (wr == g) {
        #pragma unroll
        for (int m = 0; m < 4; ++m)
          #pragma unroll
          for (int n = 0; n < 4; ++n)
            #pragma unroll
            for (int j = 0; j < 4; ++j)
              Cst[(m * 16 + gp * 4 + j) * 132 + wc * 64 + n * 16 + cl] = acc[m][n][j];
      }
      __syncthreads();
      int r2 = lane >> 5, cw = lane & 31;
      #pragma unroll
      for (int p = 0; p < 8; ++p) {
        int r = p * 8 + wave * 2 + r2;
        int grow = m0 + g * 64 + r;
        f32x4 v = *(f32x4*)&Cst[r * 132 + cw * 4];
        if constexpr (EPI == 1) {
          ushort4 rv = *(const ushort4*)&R[(size_t)grow * ldc + n0 + cw * 4];
          v[0] += bf2f(rv.x); v[1] += bf2f(rv.y); v[2] += bf2f(rv.z); v[3] += bf2f(rv.w);
        }
        if constexpr (EPI == 2) {
          #pragma unroll
          for (int j = 0; j < 4; ++j) v[j] = fmaxf(v[j], 0.f);
        }
        if (NT) __builtin_nontemporal_store(v, (f32x4*)&C[(size_t)grow * ldc + n0 + cw * 4]);
        else *(f32x4*)&C[(size_t)grow * ldc + n0 + cw * 4] = v;
      }
      __syncthreads();
    }
  } else {
    int r0 = gp * 4;
    #pragma unroll
    for (int m = 0; m < 4; ++m) {
      #pragma unroll
      for (int n = 0; n < NF; ++n) {
        int col = n0 + wc * (BN / 2) + n * 16 + cl;
        #pragma unroll
        for (int j = 0; j < 4; ++j) {
          int row = m0 + wr * 64 + m * 16 + r0 + j;
          float v = acc[m][n][j];
          if (EPI == 1) v += bf2f(R[(size_t)row * ldc + col]);
          if (EPI == 2) v = fmaxf(v, 0.f);
          if (WF32) C[(size_t)row * ldc + col] = v;
          if (WB16) Cb[(size_t)row * ldc + col] = f2bf(v);
        }
      }
    }
  }
}

// ======================================================================
// 256x256 GEMM, 8 waves (2Mx4N), 8-PHASE schedule (m201 style), 128KB dbuf.
// Half-tile stream: per tile order [B-lo, B-hi, A-lo, A-hi], lead 7 half-tiles,
// 3 in flight; vmcnt(6) once per K-tile (vmcnt(0) entering last tile).
// Requires nk >= 2.  Residual R bf16.
template<int EPI, bool WF32, bool WB16, bool SWZ, bool NT = false>
__global__ __launch_bounds__(512, 2) void gemm256(
    const u16* __restrict__ A, const u16* __restrict__ B,
    float* __restrict__ C, u16* __restrict__ Cb,
    const u16* __restrict__ R, int K, int ldc)
{
  __shared__ __align__(16) u16 smem[2][32768];   // per buf: A[256][64] @0, B[256][64] @16384
  int tid = threadIdx.x;
  int lane = tid & 63, wave = tid >> 6;
  int wr = wave >> 2, wc = wave & 3;
  int cl = lane & 15, gp = (lane >> 4) & 3;

  int bx = blockIdx.x, by = blockIdx.y;
  if (SWZ) {
    int nwg = gridDim.x * gridDim.y;
    int flat = by * gridDim.x + bx;
    int cpx = nwg >> 3;
    int swz = (flat & 7) * cpx + (flat >> 3);
    bx = swz % gridDim.x; by = swz / gridDim.x;
  }
  int m0 = bx * 256, n0 = by * 256;

  int srow8 = lane >> 3;
  int scol = (((lane & 7) - srow8) & 7) * 8;
  int pos0 = ((gp + cl) & 7) * 8;
  int pos1 = ((gp + cl + 4) & 7) * 8;

  f32x4 acc[8][4] = {};
  int nk = K >> 6;
  int hmax = nk << 2;

  // stage half-tile h: tile tau=h>>2, slot s=h&3 (0=B-lo,1=B-hi,2=A-lo,3=A-hi)
  auto stageH = [&](int h) {
    if (h >= hmax) return;
    int tau = h >> 2, s = h & 3;
    int high = (s & 1) ? 128 : 0;
    int boff = ((s < 2) ? 16384 : 0) + ((s & 1) ? 8192 : 0);
    const u16* src = (s < 2) ? B : A;
    int g0 = ((s < 2) ? n0 : m0) + high;
    int kb = tau << 6;
    #pragma unroll
    for (int i = 0; i < 2; ++i) {
      int c = wave * 2 + i;
      GLDS(src + (size_t)(g0 + c * 8 + srow8) * K + kb + scol,
           &smem[tau & 1][boff + c * 512]);
    }
  };

  // prologue: half-tiles 0..6
  for (int h = 0; h < 7; ++h) stageH(h);
  VMCNT6;                       // tile 0 landed; h4..h6 in flight
  SCHEDB; CFENCE;
  SBAR;
  CFENCE;

  for (int t = 0; t < nk; ++t) {
    const u16* Ab = &smem[t & 1][0];
    const u16* Bb2 = &smem[t & 1][16384];
    int p0 = t << 2;
    bf16x8 af0[4][2], af1[4][2], bf0[2][2], bf1[2][2];

    // ---- phase r=0: read af0,bf0,bf1; stage h=p0+7; MFMA af0 x bf0
    #pragma unroll
    for (int n = 0; n < 2; ++n) {
      int r = (wc * 64 + n * 16 + cl) * 64;
      bf0[n][0] = *(const bf16x8*)&Bb2[r + pos0];
      bf0[n][1] = *(const bf16x8*)&Bb2[r + pos1];
    }
    #pragma unroll
    for (int n = 0; n < 2; ++n) {
      int r = (wc * 64 + (n + 2) * 16 + cl) * 64;
      bf1[n][0] = *(const bf16x8*)&Bb2[r + pos0];
      bf1[n][1] = *(const bf16x8*)&Bb2[r + pos1];
    }
    #pragma unroll
    for (int m = 0; m < 4; ++m) {
      int r = (wr * 128 + m * 16 + cl) * 64;
      af0[m][0] = *(const bf16x8*)&Ab[r + pos0];
      af0[m][1] = *(const bf16x8*)&Ab[r + pos1];
    }
    stageH(p0 + 7);
    CFENCE;
    SBAR;
    LGKM0; SCHEDB;
    __builtin_amdgcn_s_setprio(1);
    #pragma unroll
    for (int m = 0; m < 4; ++m)
      #pragma unroll
      for (int n = 0; n < 2; ++n)
        #pragma unroll
        for (int ks = 0; ks < 2; ++ks)
          acc[m][n] = MFMA(af0[m][ks], bf0[n][ks], acc[m][n]);
    __builtin_amdgcn_s_setprio(0);
    CFENCE;
    SBAR;

    // ---- phase r=1: stage h=p0+8; MFMA af0 x bf1
    stageH(p0 + 8);
    CFENCE;
    SBAR;
    __builtin_amdgcn_s_setprio(1);
    #pragma unroll
    for (int m = 0; m < 4; ++m)
      #pragma unroll
      for (int n = 0; n < 2; ++n)
        #pragma unroll
        for (int ks = 0; ks < 2; ++ks)
          acc[m][n + 2] = MFMA(af0[m][ks], bf1[n][ks], acc[m][n + 2]);
    __builtin_amdgcn_s_setprio(0);
    CFENCE;
    SBAR;

    // ---- phase r=2: read af1; stage h=p0+9; MFMA af1 x bf0
    #pragma unroll
    for (int m = 0; m < 4; ++m) {
      int r = (wr * 128 + (m + 4) * 16 + cl) * 64;
      af1[m][0] = *(const bf16x8*)&Ab[r + pos0];
      af1[m][1] = *(const bf16x8*)&Ab[r + pos1];
    }
    stageH(p0 + 9);
    CFENCE;
    SBAR;
    LGKM0; SCHEDB;
    __builtin_amdgcn_s_setprio(1);
    #pragma unroll
    for (int m = 0; m < 4; ++m)
      #pragma unroll
      for (int n = 0; n < 2; ++n)
        #pragma unroll
        for (int ks = 0; ks < 2; ++ks)
          acc[m + 4][n] = MFMA(af1[m][ks], bf0[n][ks], acc[m + 4][n]);
    __builtin_amdgcn_s_setprio(0);
    CFENCE;
    SBAR;

    // ---- phase r=3: stage h=p0+10; MFMA af1 x bf1; boundary vmcnt
    stageH(p0 + 10);
    __builtin_amdgcn_s_setprio(1);
    #pragma unroll
    for (int m = 0; m < 4; ++m)
      #pragma unroll
      for (int n = 0; n < 2; ++n)
        #pragma unroll
        for (int ks = 0; ks < 2; ++ks)
          acc[m + 4][n + 2] = MFMA(af1[m][ks], bf1[n][ks], acc[m + 4][n + 2]);
    __builtin_amdgcn_s_setprio(0);
    if (t + 1 < nk) {
      if (t + 2 == nk) { VMCNT0; } else { VMCNT6; }
    }
    SCHEDB; CFENCE;
    SBAR;
    CFENCE;
  }

  if constexpr (WF32 && !WB16) {
    float* Cst = (float*)&smem[0][0];
    __syncthreads();
    #pragma unroll
    for (int g = 0; g < 4; ++g) {
      if ((g >> 1) == wr) {
        #pragma unroll
        for (int k = 0; k < 4; ++k) {
          int ar = (g & 1) * 4 + k;
          int rl = ar * 16 + gp * 4 - (g & 1) * 64;
          #pragma unroll
          for (int n = 0; n < 4; ++n) {
            int col = wc * 64 + n * 16 + cl;
            #pragma unroll
            for (int j = 0; j < 4; ++j)
              Cst[(rl + j) * 260 + col] = acc[ar][n][j];
          }
        }
      }
      __syncthreads();
      #pragma unroll
      for (int p = 0; p < 8; ++p) {
        int r = p * 8 + wave;
        int c4 = lane * 4;
        int grow = m0 + g * 64 + r;
        f32x4 v = *(f32x4*)&Cst[r * 260 + c4];
        if constexpr (EPI == 1) {
          ushort4 rv = *(const ushort4*)&R[(size_t)grow * ldc + n0 + c4];
          v[0] += bf2f(rv.x); v[1] += bf2f(rv.y); v[2] += bf2f(rv.z); v[3] += bf2f(rv.w);
        }
        if constexpr (EPI == 2) {
          #pragma unroll
          for (int j = 0; j < 4; ++j) v[j] = fmaxf(v[j], 0.f);
        }
        if (NT) __builtin_nontemporal_store(v, (f32x4*)&C[(size_t)grow * ldc + n0 + c4]);
        else *(f32x4*)&C[(size_t)grow * ldc + n0 + c4] = v;
      }
      __syncthreads();
    }
  } else {
    int r0 = gp * 4;
    #pragma unroll
    for (int m = 0; m < 8; ++m) {
      #pragma unroll
      for (int n = 0; n < 4; ++n) {
        int col = n0 + wc * 64 + n * 16 + cl;
        #pragma unroll
        for (int j = 0; j < 4; ++j) {
          int row = m0 + wr * 128 + m * 16 + r0 + j;
          float v = acc[m][n][j];
          if (EPI == 1) v += bf2f(R[(size_t)row * ldc + col]);
          if (EPI == 2) v = fmaxf(v, 0.f);
          if (WF32) C[(size_t)row * ldc + col] = v;
          if (WB16) Cb[(size_t)row * ldc + col] = f2bf(v);
        }
      }
    }
  }
}

// ---------------- fused causal attention, PAIRED q-blocks (round-10 verified)
#define LSTR 72
__global__ __launch_bounds__(256) void attn_kernel(const u16* __restrict__ qkv,
                                                   u16* __restrict__ outb) {
  __shared__ u16 Ksm[2][64 * 64];
  __shared__ u16 Vsm[2][64 * LSTR];
  __shared__ u16 Psm[64 * LSTR];
  int pi = blockIdx.x, h = blockIdx.y, b = blockIdx.z;
  int qbA = pi, qbB = 15 - pi;
  int tid = threadIdx.x;
  int lane = tid & 63, wave = tid >> 6;
  int cl = lane & 15, gp = lane >> 4;
  int srow8 = lane >> 3;
  int gsrc = (((lane & 7) - srow8) & 7) * 8;

  const u16* base = qkv + (size_t)b * SEQLEN * (3 * HIDDEN);

  bf16x8 qA0, qA1, qB0, qB1;
  {
    const u16* qp = base + (size_t)(qbA * 64 + wave * 16 + cl) * (3 * HIDDEN) + h * HDIM;
    qA0 = *(const bf16x8*)(qp + gp * 8);
    qA1 = *(const bf16x8*)(qp + 32 + gp * 8);
    const u16* qq = base + (size_t)(qbB * 64 + wave * 16 + cl) * (3 * HIDDEN) + h * HDIM;
    qB0 = *(const bf16x8*)(qq + gp * 8);
    qB1 = *(const bf16x8*)(qq + 32 + gp * 8);
  }

  ushort4 vr[4];
  auto stageK = [&](int t, int bb) {
    #pragma unroll
    for (int i = 0; i < 2; ++i) {
      int c = wave * 2 + i;
      int row = c * 8 + srow8;
      GLDS(base + (size_t)(t * 64 + row) * (3 * HIDDEN) + HIDDEN + h * HDIM + gsrc,
           &Ksm[bb][c * 512]);
    }
  };
  auto loadV = [&](int t) {
    #pragma unroll
    for (int it = 0; it < 4; ++it) {
      int idx = it * 256 + tid;
      int row = idx >> 4, c4 = (idx & 15) * 4;
      vr[it] = *(const ushort4*)(base + (size_t)(t * 64 + row) * (3 * HIDDEN) +
                                 2 * HIDDEN + h * HDIM + c4);
    }
  };
  auto writeV = [&](int bb) {
    #pragma unroll
    for (int it = 0; it < 4; ++it) {
      int idx = it * 256 + tid;
      int row = idx >> 4, c4 = (idx & 15) * 4;
      Vsm[bb][(c4 + 0) * LSTR + row] = vr[it].x;
      Vsm[bb][(c4 + 1) * LSTR + row] = vr[it].y;
      Vsm[bb][(c4 + 2) * LSTR + row] = vr[it].z;
      Vsm[bb][(c4 + 3) * LSTR + row] = vr[it].w;
    }
  };

  float mA[4], lA[4], mB[4], lB[4];
  f32x4 oA[4] = {}, oB[4] = {};
  #pragma unroll
  for (int j = 0; j < 4; ++j) { mA[j] = -INFINITY; lA[j] = 0.f; mB[j] = -INFINITY; lB[j] = 0.f; }

  auto stateStep = [&](int t, int buf, int qb, bf16x8 q0, bf16x8 q1,
                       float* mrow, float* lrow, f32x4* oacc) {
    f32x4 sfr[4];
    __builtin_amdgcn_s_setprio(1);
    #pragma unroll
    for (int n = 0; n < 4; ++n) {
      f32x4 z = {};
      bf16x8 kf0 = *(const bf16x8*)&Ksm[buf][(n * 16 + cl) * 64 + ((gp + cl) & 7) * 8];
      bf16x8 kf1 = *(const bf16x8*)&Ksm[buf][(n * 16 + cl) * 64 + ((gp + cl + 4) & 7) * 8];
      z = MFMA(q0, kf0, z);
      z = MFMA(q1, kf1, z);
      sfr[n] = z;
    }
    __builtin_amdgcn_s_setprio(0);

    bool diag = (t == qb);
    #pragma unroll
    for (int n = 0; n < 4; ++n)
      #pragma unroll
      for (int j = 0; j < 4; ++j) {
        float sv = sfr[n][j] * 0.03125f;
        if (diag) {
          int lr = wave * 16 + gp * 4 + j;
          int lc = n * 16 + cl;
          sv = (lc <= lr) ? sv : -1e30f;
        }
        sfr[n][j] = sv;
      }
    float so[4];
    #pragma unroll
    for (int j = 0; j < 4; ++j) {
      float tm = fmaxf(fmaxf(sfr[0][j], sfr[1][j]), fmaxf(sfr[2][j], sfr[3][j]));
      tm = fmaxf(tm, __shfl_xor(tm, 1));
      tm = fmaxf(tm, __shfl_xor(tm, 2));
      tm = fmaxf(tm, __shfl_xor(tm, 4));
      tm = fmaxf(tm, __shfl_xor(tm, 8));
      float mn = fmaxf(mrow[j], tm);
      so[j] = __expf(mrow[j] - mn);
      mrow[j] = mn;
      float ts = 0.f;
      #pragma unroll
      for (int n = 0; n < 4; ++n) {
        float p = __expf(sfr[n][j] - mn);
        sfr[n][j] = p;
        ts += p;
      }
      ts += __shfl_xor(ts, 1); ts += __shfl_xor(ts, 2);
      ts += __shfl_xor(ts, 4); ts += __shfl_xor(ts, 8);
      lrow[j] = lrow[j] * so[j] + ts;
    }
    #pragma unroll
    for (int n = 0; n < 4; ++n)
      #pragma unroll
      for (int j = 0; j < 4; ++j)
        oacc[n][j] *= so[j];

    #pragma unroll
    for (int n = 0; n < 4; ++n)
      #pragma unroll
      for (int j = 0; j < 4; ++j)
        Psm[(wave * 16 + gp * 4 + j) * LSTR + n * 16 + cl] = f2bf(sfr[n][j]);
    __builtin_amdgcn_sched_barrier(0);

    bf16x8 pa0 = *(const bf16x8*)&Psm[(wave * 16 + cl) * LSTR + gp * 8];
    bf16x8 pa1 = *(const bf16x8*)&Psm[(wave * 16 + cl) * LSTR + 32 + gp * 8];
    __builtin_amdgcn_s_setprio(1);
    #pragma unroll
    for (int n = 0; n < 4; ++n) {
      bf16x8 vb0 = *(const bf16x8*)&Vsm[buf][(n * 16 + cl) * LSTR + gp * 8];
      bf16x8 vb1 = *(const bf16x8*)&Vsm[buf][(n * 16 + cl) * LSTR + 32 + gp * 8];
      oacc[n] = MFMA(pa0, vb0, oacc[n]);
      oacc[n] = MFMA(pa1, vb1, oacc[n]);
    }
    __builtin_amdgcn_s_setprio(0);
  };

  stageK(0, 0);
  loadV(0);
  writeV(0);
  __syncthreads();

  for (int t = 0; t <= qbB; ++t) {
    int buf = t & 1;
    bool more = t < qbB;
    if (more) { stageK(t + 1, buf ^ 1); loadV(t + 1); }

    stateStep(t, buf, qbB, qB0, qB1, mB, lB, oB);
    if (more) writeV(buf ^ 1);
    if (t <= qbA)
      stateStep(t, buf, qbA, qA0, qA1, mA, lA, oA);

    __syncthreads();
  }

  #pragma unroll
  for (int n = 0; n < 4; ++n)
    #pragma unroll
    for (int j = 0; j < 4; ++j) {
      int lr = wave * 16 + gp * 4 + j;
      int d = n * 16 + cl;
      outb[(size_t)(b * SEQLEN + qbA * 64 + lr) * HIDDEN + h * HDIM + d] = f2bf(oA[n][j] / lA[j]);
      outb[(size_t)(b * SEQLEN + qbB * 64 + lr) * HIDDEN + h * HDIM + d] = f2bf(oB[n][j] / lB[j]);
    }
}

extern "C" void kernel_launch(void* const* d_in, const int* in_sizes, int n_in,
                              void* d_out, int out_size, void* d_ws, size_t ws_size,
                              hipStream_t stream) {
  const int*   ids    = (const int*)d_in[0];
  const float* W_word = (const float*)d_in[1];
  const float* W_pos  = (const float*)d_in[2];
  const float* Wq     = (const float*)d_in[3];
  const float* Wk     = (const float*)d_in[4];
  const float* Wv     = (const float*)d_in[5];
  const float* Wo     = (const float*)d_in[6];
  const float* W1     = (const float*)d_in[7];
  const float* W2     = (const float*)d_in[8];
  const float* W_eh   = (const float*)d_in[9];
  const float* W_he   = (const float*)d_in[10];
  const float* W_lm   = (const float*)d_in[11];
  float* out = (float*)d_out;
  char*  ob  = (char*)d_out;
  char*  wb  = (char*)d_ws;

  const size_t MB = 1024 * 1024;
  u16*   h0b   = (u16*)(ob + 32 * MB);
  u16*   h1b   = (u16*)(ob + 36 * MB);
  u16*   qkvb  = (u16*)(ob + 44 * MB);
  u16*   attnb = (u16*)(ob + 68 * MB);
  u16*   h2b   = (u16*)(ob + 76 * MB);
  u16*   xb    = (u16*)(ob + 84 * MB);
  u16*   h3b   = (u16*)(ob + 116 * MB);
  u16*   Wqkv_b= (u16*)(ob + 124 * MB);
  u16*   Wo_b  = (u16*)(ob + 130 * MB);
  u16*   W1_b  = (u16*)(ob + 132 * MB);
  u16*   W2_b  = (u16*)(ob + 140 * MB);
  u16*   Weh_b = (u16*)(ob + 148 * MB);
  u16*   Whe_b = (u16*)(ob + 149 * MB);
  u16*   he_b  = (u16*)(wb + 0);
  u16*   Wlm_b = (u16*)(wb + 4 * MB);
  bool big_ws = ws_size >= 36 * MB;

  Prep pp;
  pp.src[0] = Wq;  pp.dst[0] = Wqkv_b + 0 * 1024 * 1024;
  pp.src[1] = Wk;  pp.dst[1] = Wqkv_b + 1 * 1024 * 1024;
  pp.src[2] = Wv;  pp.dst[2] = Wqkv_b + 2 * 1024 * 1024;
  pp.src[3] = Wo;  pp.dst[3] = Wo_b;
  pp.src[4] = W1;  pp.dst[4] = W1_b;
  pp.src[5] = W2;  pp.dst[5] = W2_b;
  pp.src[6] = W_eh; pp.dst[6] = Weh_b;
  pp.src[7] = W_he; pp.dst[7] = Whe_b;
  pp.wlm = W_lm; pp.wlm_dst = big_ws ? Wlm_b : nullptr;
  pp.ids = ids; pp.wword = W_word; pp.wpos = W_pos; pp.h0b = h0b;
  prep_kernel<<<dim3(31360), 256, 0, stream>>>(pp);

  // h1b = h0 @ W_eh.T
  gemm128<0, false, true, false, false, false, 128><<<dim3(32, 8), 256, 0, stream>>>(
      h0b, Weh_b, nullptr, nullptr, h1b, nullptr, 512, HIDDEN);
  // qkv = h1 @ Wqkv.T
  gemm128<0, false, true, false, false, false, 128><<<dim3(32, 24), 256, 0, stream>>>(
      h1b, Wqkv_b, nullptr, nullptr, qkvb, nullptr, 1024, 3 * HIDDEN);
  // attention (paired q-blocks)
  attn_kernel<<<dim3(8, 16, 4), 256, 0, stream>>>(qkvb, attnb);
  // h2b = h1b + attn @ Wo.T
  gemm128<1, false, true, false, false, false, 128><<<dim3(32, 8), 256, 0, stream>>>(
      attnb, Wo_b, nullptr, nullptr, h2b, h1b, 1024, HIDDEN);
  // x = relu(h2 @ W1.T)          (8-phase 256^2, nk=16)
  gemm256<2, false, true, false><<<dim3(16, 16), 512, 0, stream>>>(
      h2b, W1_b, nullptr, xb, nullptr, 1024, 4 * HIDDEN);
  // h3b = h2b + x @ W2.T
  gemm128<1, false, true, false, false, false, 128><<<dim3(32, 8), 256, 0, stream>>>(
      xb, W2_b, nullptr, nullptr, h3b, h2b, 4096, HIDDEN);
  // he = h3 @ W_he.T             (BN=64)
  gemm128<0, false, true, false, false, false, 64><<<dim3(32, 8), 256, 0, stream>>>(
      h3b, Whe_b, nullptr, nullptr, he_b, nullptr, 1024, EMBED);
  // logits = he @ W_lm.T         (8-phase 256^2, nk=8, coalesced NT epilogue)
  if (big_ws)
    gemm256<0, true, false, true, true><<<dim3(16, 125), 512, 0, stream>>>(
        he_b, Wlm_b, out, nullptr, nullptr, 512, VOCAB);
  else
    gemm128<0, true, false, true, true, true, 128><<<dim3(32, 250), 256, 0, stream>>>(
        he_b, nullptr, W_lm, out, nullptr, nullptr, 512, VOCAB);
}

// Round 12
// 401.662 us; speedup vs baseline: 1.0815x; 1.0815x over previous
//
#include <hip/hip_runtime.h>
#include <hip/hip_bf16.h>

#define HIDDEN 1024
#define NHEAD 16
#define HDIM 64
#define VOCAB 32000
#define SEQLEN 1024
#define EMBED 512
#define BATCH 4
#define ROWS (BATCH*SEQLEN)   // 4096

typedef __bf16 bf16x8 __attribute__((ext_vector_type(8)));
typedef float f32x4 __attribute__((ext_vector_type(4)));
typedef unsigned short u16;

#define MFMA(a_, b_, c_) __builtin_amdgcn_mfma_f32_16x16x32_bf16(a_, b_, c_, 0, 0, 0)

#define VMCNT4 asm volatile("s_waitcnt vmcnt(4)" ::: "memory")
#define VMCNT0 asm volatile("s_waitcnt vmcnt(0)" ::: "memory")
#define LGKM0  asm volatile("s_waitcnt lgkmcnt(0)" ::: "memory")
#define CFENCE asm volatile("" ::: "memory")
#define SBAR   __builtin_amdgcn_s_barrier()
#define SCHEDB __builtin_amdgcn_sched_barrier(0)

__device__ __forceinline__ u16 f2bf(float f) {
  unsigned u = __builtin_bit_cast(unsigned, f);
  u = u + 0x7FFFu + ((u >> 16) & 1u);
  return (u16)(u >> 16);
}
__device__ __forceinline__ float bf2f(u16 s) {
  unsigned u = (unsigned)s << 16;
  return __builtin_bit_cast(float, u);
}

// async global->LDS, 16B/lane; LDS dest = wave-uniform base + lane*16
#define GLDS(g_, l_) __builtin_amdgcn_global_load_lds( \
    (const __attribute__((address_space(1))) void*)(g_), \
    (__attribute__((address_space(3))) void*)(l_), 16, 0, 0)

// ---------------- fused prep: 8 small weight cvts + W_lm cvt + embedding
struct Prep {
  const float* src[8]; u16* dst[8];
  const float* wlm; u16* wlm_dst;
  const int* ids; const float* wword; const float* wpos; u16* h0b;
};
__global__ void prep_kernel(Prep pp) {
  int b = blockIdx.x;
  if (b < 13312) {
    int seg, off;
    if (b < 4096)        { seg = b >> 10; off = b & 1023; }
    else if (b < 8192)   { seg = 4; off = b - 4096; }
    else if (b < 12288)  { seg = 5; off = b - 8192; }
    else if (b < 12800)  { seg = 6; off = b - 12288; }
    else                 { seg = 7; off = b - 12800; }
    size_t i = ((size_t)off * 256 + threadIdx.x) * 4;
    float4 v = *(const float4*)(pp.src[seg] + i);
    unsigned a = f2bf(v.x) | ((unsigned)f2bf(v.y) << 16);
    unsigned d = f2bf(v.z) | ((unsigned)f2bf(v.w) << 16);
    *(uint2*)(pp.dst[seg] + i) = make_uint2(a, d);
  } else if (b < 29312) {
    if (!pp.wlm_dst) return;
    int off = b - 13312;
    size_t i = ((size_t)off * 256 + threadIdx.x) * 4;
    float4 v = *(const float4*)(pp.wlm + i);
    unsigned a = f2bf(v.x) | ((unsigned)f2bf(v.y) << 16);
    unsigned d = f2bf(v.z) | ((unsigned)f2bf(v.w) << 16);
    *(uint2*)(pp.wlm_dst + i) = make_uint2(a, d);
  } else {
    int off = b - 29312;
    int row = off * 2 + (threadIdx.x >> 7);
    int e = (threadIdx.x & 127) * 4;
    int s = row & (SEQLEN - 1);
    int id = pp.ids[row];
    float4 a = *(const float4*)(pp.wword + (size_t)id * EMBED + e);
    float4 c = *(const float4*)(pp.wpos + (size_t)s * EMBED + e);
    unsigned lo = f2bf(a.x + c.x) | ((unsigned)f2bf(a.y + c.y) << 16);
    unsigned hi = f2bf(a.z + c.z) | ((unsigned)f2bf(a.w + c.w) << 16);
    *(uint2*)(pp.h0b + (size_t)row * EMBED + e) = make_uint2(lo, hi);
  }
}

// ======================================================================
// 128xBN GEMM, 4 waves, dbuf LDS, rotation-swizzled, counted-vmcnt dual-barrier.
template<int EPI, bool WF32, bool WB16, bool BF32, bool SWZ, bool NT, int BN>
__global__ __launch_bounds__(256, 2) void gemm128(
    const u16* __restrict__ A, const u16* __restrict__ Bb,
    const float* __restrict__ Bf,
    float* __restrict__ C, u16* __restrict__ Cb,
    const u16* __restrict__ R, int K, int ldc)
{
  constexpr int NF  = BN / 32;
  constexpr int BCH = BN / 32;
  __shared__ __align__(16) u16 smem[16384 + 2 * BN * 64];
  u16* As0 = &smem[0];
  u16* As1 = &smem[8192];
  u16* Bs0 = &smem[16384];
  u16* Bs1 = &smem[16384 + BN * 64];

  int tid = threadIdx.x;
  int lane = tid & 63, wave = tid >> 6;
  int wr = wave >> 1, wc = wave & 1;
  int cl = lane & 15, gp = (lane >> 4) & 3;

  int bx = blockIdx.x, by = blockIdx.y;
  if (SWZ) {
    int nwg = gridDim.x * gridDim.y;
    int flat = by * gridDim.x + bx;
    int cpx = nwg >> 3;
    int swz = (flat & 7) * cpx + (flat >> 3);
    bx = swz % gridDim.x; by = swz / gridDim.x;
  }
  int m0 = bx * 128, n0 = by * BN;

  int srow8 = lane >> 3;
  int scol = (((lane & 7) - srow8) & 7) * 8;
  int pos0 = ((gp + cl) & 7) * 8;
  int pos1 = ((gp + cl + 4) & 7) * 8;

  f32x4 acc[4][NF] = {};
  int nk = K >> 6;

  #pragma unroll
  for (int i = 0; i < 4; ++i) {
    int c = i * 4 + wave;
    GLDS(A + (size_t)(m0 + c * 8 + srow8) * K + scol, As0 + c * 512);
  }
  if (!BF32) {
    #pragma unroll
    for (int i = 0; i < BCH; ++i) {
      int c = i * 4 + wave;
      GLDS(Bb + (size_t)(n0 + c * 8 + srow8) * K + scol, Bs0 + c * 512);
    }
  } else {
    #pragma unroll
    for (int it = 0; it < BN / 32; ++it) {
      int idx = it * 256 + tid;
      int row = idx >> 3, p = idx & 7;
      int gc = (p - row) & 7;
      const float* src = Bf + (size_t)(n0 + row) * K + gc * 8;
      float4 v0 = *(const float4*)src, v1 = *(const float4*)(src + 4);
      union { bf16x8 v; u16 s[8]; } u;
      u.s[0]=f2bf(v0.x); u.s[1]=f2bf(v0.y); u.s[2]=f2bf(v0.z); u.s[3]=f2bf(v0.w);
      u.s[4]=f2bf(v1.x); u.s[5]=f2bf(v1.y); u.s[6]=f2bf(v1.z); u.s[7]=f2bf(v1.w);
      *(bf16x8*)&Bs0[row * 64 + p * 8] = u.v;
    }
  }

  for (int kt = 0; kt < nk; ++kt) {
    int buf = kt & 1;
    u16* Asb = buf ? As1 : As0;
    u16* Bsb = buf ? Bs1 : Bs0;
    u16* Asn = buf ? As0 : As1;
    u16* Bsn = buf ? Bs0 : Bs1;
    int kb = (kt + 1) << 6;
    bool more = kt + 1 < nk;

    if (more) {
      #pragma unroll
      for (int i = 0; i < 4; ++i) {
        int c = i * 4 + wave;
        GLDS(A + (size_t)(m0 + c * 8 + srow8) * K + kb + scol, Asn + c * 512);
      }
    }
    if (BF32) { VMCNT0; } else if (more) { VMCNT4; } else { VMCNT0; }
    SCHEDB;
    SBAR;
    CFENCE; SCHEDB;

    bf16x8 af[4][2], bfv[NF][2];
    #pragma unroll
    for (int n = 0; n < NF; ++n) {
      int r = (wc * (BN / 2) + n * 16 + cl) * 64;
      bfv[n][0] = *(const bf16x8*)&Bsb[r + pos0];
      bfv[n][1] = *(const bf16x8*)&Bsb[r + pos1];
    }
    #pragma unroll
    for (int m = 0; m < 4; ++m) {
      int r = (wr * 64 + m * 16 + cl) * 64;
      af[m][0] = *(const bf16x8*)&Asb[r + pos0];
      af[m][1] = *(const bf16x8*)&Asb[r + pos1];
    }

    __builtin_amdgcn_s_setprio(1);
    #pragma unroll
    for (int m = 0; m < 2; ++m)
      #pragma unroll
      for (int n = 0; n < NF; ++n)
        #pragma unroll
        for (int ks = 0; ks < 2; ++ks)
          acc[m][n] = MFMA(af[m][ks], bfv[n][ks], acc[m][n]);
    __builtin_amdgcn_s_setprio(0);

    if (more) {
      if (!BF32) {
        #pragma unroll
        for (int i = 0; i < BCH; ++i) {
          int c = i * 4 + wave;
          GLDS(Bb + (size_t)(n0 + c * 8 + srow8) * K + kb + scol, Bsn + c * 512);
        }
      } else {
        #pragma unroll
        for (int it = 0; it < BN / 32; ++it) {
          int idx = it * 256 + tid;
          int row = idx >> 3, p = idx & 7;
          int gc = (p - row) & 7;
          const float* src = Bf + (size_t)(n0 + row) * K + kb + gc * 8;
          float4 v0 = *(const float4*)src, v1 = *(const float4*)(src + 4);
          union { bf16x8 v; u16 s[8]; } u;
          u.s[0]=f2bf(v0.x); u.s[1]=f2bf(v0.y); u.s[2]=f2bf(v0.z); u.s[3]=f2bf(v0.w);
          u.s[4]=f2bf(v1.x); u.s[5]=f2bf(v1.y); u.s[6]=f2bf(v1.z); u.s[7]=f2bf(v1.w);
          *(bf16x8*)&Bsn[row * 64 + p * 8] = u.v;
        }
      }
    }

    __builtin_amdgcn_s_setprio(1);
    #pragma unroll
    for (int n = 0; n < NF; ++n)
      #pragma unroll
      for (int ks = 0; ks < 2; ++ks)
        acc[2][n] = MFMA(af[2][ks], bfv[n][ks], acc[2][n]);
    __builtin_amdgcn_s_setprio(0);

    LGKM0;
    SCHEDB;
    SBAR;
    CFENCE; SCHEDB;

    __builtin_amdgcn_s_setprio(1);
    #pragma unroll
    for (int n = 0; n < NF; ++n)
      #pragma unroll
      for (int ks = 0; ks < 2; ++ks)
        acc[3][n] = MFMA(af[3][ks], bfv[n][ks], acc[3][n]);
    __builtin_amdgcn_s_setprio(0);
  }

  if constexpr (WF32 && !WB16 && BN == 128) {
    float* Cst = (float*)&smem[0];
    __syncthreads();
    #pragma unroll
    for (int g = 0; g < 2; ++g) {
      if (wr == g) {
        #pragma unroll
        for (int m = 0; m < 4; ++m)
          #pragma unroll
          for (int n = 0; n < 4; ++n)
            #pragma unroll
            for (int j = 0; j < 4; ++j)
              Cst[(m * 16 + gp * 4 + j) * 132 + wc * 64 + n * 16 + cl] = acc[m][n][j];
      }
      __syncthreads();
      int r2 = lane >> 5, cw = lane & 31;
      #pragma unroll
      for (int p = 0; p < 8; ++p) {
        int r = p * 8 + wave * 2 + r2;
        int grow = m0 + g * 64 + r;
        f32x4 v = *(f32x4*)&Cst[r * 132 + cw * 4];
        if constexpr (EPI == 1) {
          ushort4 rv = *(const ushort4*)&R[(size_t)grow * ldc + n0 + cw * 4];
          v[0] += bf2f(rv.x); v[1] += bf2f(rv.y); v[2] += bf2f(rv.z); v[3] += bf2f(rv.w);
        }
        if constexpr (EPI == 2) {
          #pragma unroll
          for (int j = 0; j < 4; ++j) v[j] = fmaxf(v[j], 0.f);
        }
        if (NT) __builtin_nontemporal_store(v, (f32x4*)&C[(size_t)grow * ldc + n0 + cw * 4]);
        else *(f32x4*)&C[(size_t)grow * ldc + n0 + cw * 4] = v;
      }
      __syncthreads();
    }
  } else {
    int r0 = gp * 4;
    #pragma unroll
    for (int m = 0; m < 4; ++m) {
      #pragma unroll
      for (int n = 0; n < NF; ++n) {
        int col = n0 + wc * (BN / 2) + n * 16 + cl;
        #pragma unroll
        for (int j = 0; j < 4; ++j) {
          int row = m0 + wr * 64 + m * 16 + r0 + j;
          float v = acc[m][n][j];
          if (EPI == 1) v += bf2f(R[(size_t)row * ldc + col]);
          if (EPI == 2) v = fmaxf(v, 0.f);
          if (WF32) C[(size_t)row * ldc + col] = v;
          if (WB16) Cb[(size_t)row * ldc + col] = f2bf(v);
        }
      }
    }
  }
}

// ======================================================================
// 256x256 GEMM, 8 waves (2Mx4N), 128KB dbuf LDS, counted-vmcnt dual-barrier.
// (round-10 verified version)
template<int EPI, bool WF32, bool WB16, bool SWZ, bool NT = false>
__global__ __launch_bounds__(512) void gemm256(
    const u16* __restrict__ A, const u16* __restrict__ B,
    float* __restrict__ C, u16* __restrict__ Cb,
    const u16* __restrict__ R, int K, int ldc)
{
  __shared__ __align__(16) u16 smem[4][256 * 64];
  int tid = threadIdx.x;
  int lane = tid & 63, wave = tid >> 6;
  int wr = wave >> 2, wc = wave & 3;
  int cl = lane & 15, gp = (lane >> 4) & 3;

  int bx = blockIdx.x, by = blockIdx.y;
  if (SWZ) {
    int nwg = gridDim.x * gridDim.y;
    int flat = by * gridDim.x + bx;
    int cpx = nwg >> 3;
    int swz = (flat & 7) * cpx + (flat >> 3);
    bx = swz % gridDim.x; by = swz / gridDim.x;
  }
  int m0 = bx * 256, n0 = by * 256;

  int srow8 = lane >> 3;
  int scol = (((lane & 7) - srow8) & 7) * 8;
  int pos0 = ((gp + cl) & 7) * 8;
  int pos1 = ((gp + cl + 4) & 7) * 8;

  f32x4 acc[8][4] = {};
  int nk = K >> 6;

  #pragma unroll
  for (int i = 0; i < 4; ++i) {
    int c = i * 8 + wave;
    GLDS(A + (size_t)(m0 + c * 8 + srow8) * K + scol, &smem[0][c * 512]);
  }
  #pragma unroll
  for (int i = 0; i < 4; ++i) {
    int c = i * 8 + wave;
    GLDS(B + (size_t)(n0 + c * 8 + srow8) * K + scol, &smem[2][c * 512]);
  }

  for (int kt = 0; kt < nk; ++kt) {
    int buf = kt & 1;
    int kb = (kt + 1) << 6;
    bool more = kt + 1 < nk;

    if (more) {
      #pragma unroll
      for (int i = 0; i < 4; ++i) {
        int c = i * 8 + wave;
        GLDS(A + (size_t)(m0 + c * 8 + srow8) * K + kb + scol, &smem[buf ^ 1][c * 512]);
      }
      VMCNT4;
    } else {
      VMCNT0;
    }
    SCHEDB;
    SBAR;
    CFENCE; SCHEDB;

    bf16x8 af0[4][2], af1[4][2], bf0[2][2], bf1[2][2];
    #pragma unroll
    for (int n = 0; n < 2; ++n) {
      int r = (wc * 64 + n * 16 + cl) * 64;
      bf0[n][0] = *(const bf16x8*)&smem[2 + buf][r + pos0];
      bf0[n][1] = *(const bf16x8*)&smem[2 + buf][r + pos1];
    }
    #pragma unroll
    for (int m = 0; m < 4; ++m) {
      int r = (wr * 128 + m * 16 + cl) * 64;
      af0[m][0] = *(const bf16x8*)&smem[buf][r + pos0];
      af0[m][1] = *(const bf16x8*)&smem[buf][r + pos1];
    }
    #pragma unroll
    for (int n = 0; n < 2; ++n) {
      int r = (wc * 64 + (n + 2) * 16 + cl) * 64;
      bf1[n][0] = *(const bf16x8*)&smem[2 + buf][r + pos0];
      bf1[n][1] = *(const bf16x8*)&smem[2 + buf][r + pos1];
    }
    #pragma unroll
    for (int m = 0; m < 4; ++m) {
      int r = (wr * 128 + (m + 4) * 16 + cl) * 64;
      af1[m][0] = *(const bf16x8*)&smem[buf][r + pos0];
      af1[m][1] = *(const bf16x8*)&smem[buf][r + pos1];
    }

    __builtin_amdgcn_s_setprio(1);
    #pragma unroll
    for (int m = 0; m < 4; ++m)
      #pragma unroll
      for (int n = 0; n < 2; ++n)
        #pragma unroll
        for (int ks = 0; ks < 2; ++ks)
          acc[m][n] = MFMA(af0[m][ks], bf0[n][ks], acc[m][n]);
    __builtin_amdgcn_s_setprio(0);

    if (more) {
      #pragma unroll
      for (int i = 0; i < 4; ++i) {
        int c = i * 8 + wave;
        GLDS(B + (size_t)(n0 + c * 8 + srow8) * K + kb + scol, &smem[2 + (buf ^ 1)][c * 512]);
      }
    }

    __builtin_amdgcn_s_setprio(1);
    #pragma unroll
    for (int m = 0; m < 4; ++m)
      #pragma unroll
      for (int n = 0; n < 2; ++n)
        #pragma unroll
        for (int ks = 0; ks < 2; ++ks)
          acc[m][n + 2] = MFMA(af0[m][ks], bf1[n][ks], acc[m][n + 2]);
    __builtin_amdgcn_s_setprio(0);

    LGKM0;
    SCHEDB;
    SBAR;
    CFENCE; SCHEDB;

    __builtin_amdgcn_s_setprio(1);
    #pragma unroll
    for (int m = 0; m < 4; ++m)
      #pragma unroll
      for (int n = 0; n < 2; ++n)
        #pragma unroll
        for (int ks = 0; ks < 2; ++ks)
          acc[m + 4][n] = MFMA(af1[m][ks], bf0[n][ks], acc[m + 4][n]);
    #pragma unroll
    for (int m = 0; m < 4; ++m)
      #pragma unroll
      for (int n = 0; n < 2; ++n)
        #pragma unroll
        for (int ks = 0; ks < 2; ++ks)
          acc[m + 4][n + 2] = MFMA(af1[m][ks], bf1[n][ks], acc[m + 4][n + 2]);
    __builtin_amdgcn_s_setprio(0);
  }

  if constexpr (WF32 && !WB16) {
    float* Cst = (float*)&smem[0][0];
    __syncthreads();
    #pragma unroll
    for (int g = 0; g < 4; ++g) {
      if ((g >> 1) == wr) {
        #pragma unroll
        for (int k = 0; k < 4; ++k) {
          int ar = (g & 1) * 4 + k;
          int rl = ar * 16 + gp * 4 - (g & 1) * 64;
          #pragma unroll
          for (int n = 0; n < 4; ++n) {
            int col = wc * 64 + n * 16 + cl;
            #pragma unroll
            for (int j = 0; j < 4; ++j)
              Cst[(rl + j) * 260 + col] = acc[ar][n][j];
          }
        }
      }
      __syncthreads();
      #pragma unroll
      for (int p = 0; p < 8; ++p) {
        int r = p * 8 + wave;
        int c4 = lane * 4;
        int grow = m0 + g * 64 + r;
        f32x4 v = *(f32x4*)&Cst[r * 260 + c4];
        if constexpr (EPI == 1) {
          ushort4 rv = *(const ushort4*)&R[(size_t)grow * ldc + n0 + c4];
          v[0] += bf2f(rv.x); v[1] += bf2f(rv.y); v[2] += bf2f(rv.z); v[3] += bf2f(rv.w);
        }
        if constexpr (EPI == 2) {
          #pragma unroll
          for (int j = 0; j < 4; ++j) v[j] = fmaxf(v[j], 0.f);
        }
        if (NT) __builtin_nontemporal_store(v, (f32x4*)&C[(size_t)grow * ldc + n0 + c4]);
        else *(f32x4*)&C[(size_t)grow * ldc + n0 + c4] = v;
      }
      __syncthreads();
    }
  } else {
    int r0 = gp * 4;
    #pragma unroll
    for (int m = 0; m < 8; ++m) {
      #pragma unroll
      for (int n = 0; n < 4; ++n) {
        int col = n0 + wc * 64 + n * 16 + cl;
        #pragma unroll
        for (int j = 0; j < 4; ++j) {
          int row = m0 + wr * 128 + m * 16 + r0 + j;
          float v = acc[m][n][j];
          if (EPI == 1) v += bf2f(R[(size_t)row * ldc + col]);
          if (EPI == 2) v = fmaxf(v, 0.f);
          if (WF32) C[(size_t)row * ldc + col] = v;
          if (WB16) Cb[(size_t)row * ldc + col] = f2bf(v);
        }
      }
    }
  }
}

// ---------------- fused causal attention, PAIRED q-blocks (round-10 verified)
#define LSTR 72
__global__ __launch_bounds__(256) void attn_kernel(const u16* __restrict__ qkv,
                                                   u16* __restrict__ outb) {
  __shared__ u16 Ksm[2][64 * 64];
  __shared__ u16 Vsm[2][64 * LSTR];
  __shared__ u16 Psm[64 * LSTR];
  int pi = blockIdx.x, h = blockIdx.y, b = blockIdx.z;
  int qbA = pi, qbB = 15 - pi;
  int tid = threadIdx.x;
  int lane = tid & 63, wave = tid >> 6;
  int cl = lane & 15, gp = lane >> 4;
  int srow8 = lane >> 3;
  int gsrc = (((lane & 7) - srow8) & 7) * 8;

  const u16* base = qkv + (size_t)b * SEQLEN * (3 * HIDDEN);

  bf16x8 qA0, qA1, qB0, qB1;
  {
    const u16* qp = base + (size_t)(qbA * 64 + wave * 16 + cl) * (3 * HIDDEN) + h * HDIM;
    qA0 = *(const bf16x8*)(qp + gp * 8);
    qA1 = *(const bf16x8*)(qp + 32 + gp * 8);
    const u16* qq = base + (size_t)(qbB * 64 + wave * 16 + cl) * (3 * HIDDEN) + h * HDIM;
    qB0 = *(const bf16x8*)(qq + gp * 8);
    qB1 = *(const bf16x8*)(qq + 32 + gp * 8);
  }

  ushort4 vr[4];
  auto stageK = [&](int t, int bb) {
    #pragma unroll
    for (int i = 0; i < 2; ++i) {
      int c = wave * 2 + i;
      int row = c * 8 + srow8;
      GLDS(base + (size_t)(t * 64 + row) * (3 * HIDDEN) + HIDDEN + h * HDIM + gsrc,
           &Ksm[bb][c * 512]);
    }
  };
  auto loadV = [&](int t) {
    #pragma unroll
    for (int it = 0; it < 4; ++it) {
      int idx = it * 256 + tid;
      int row = idx >> 4, c4 = (idx & 15) * 4;
      vr[it] = *(const ushort4*)(base + (size_t)(t * 64 + row) * (3 * HIDDEN) +
                                 2 * HIDDEN + h * HDIM + c4);
    }
  };
  auto writeV = [&](int bb) {
    #pragma unroll
    for (int it = 0; it < 4; ++it) {
      int idx = it * 256 + tid;
      int row = idx >> 4, c4 = (idx & 15) * 4;
      Vsm[bb][(c4 + 0) * LSTR + row] = vr[it].x;
      Vsm[bb][(c4 + 1) * LSTR + row] = vr[it].y;
      Vsm[bb][(c4 + 2) * LSTR + row] = vr[it].z;
      Vsm[bb][(c4 + 3) * LSTR + row] = vr[it].w;
    }
  };

  float mA[4], lA[4], mB[4], lB[4];
  f32x4 oA[4] = {}, oB[4] = {};
  #pragma unroll
  for (int j = 0; j < 4; ++j) { mA[j] = -INFINITY; lA[j] = 0.f; mB[j] = -INFINITY; lB[j] = 0.f; }

  auto stateStep = [&](int t, int buf, int qb, bf16x8 q0, bf16x8 q1,
                       float* mrow, float* lrow, f32x4* oacc) {
    f32x4 sfr[4];
    __builtin_amdgcn_s_setprio(1);
    #pragma unroll
    for (int n = 0; n < 4; ++n) {
      f32x4 z = {};
      bf16x8 kf0 = *(const bf16x8*)&Ksm[buf][(n * 16 + cl) * 64 + ((gp + cl) & 7) * 8];
      bf16x8 kf1 = *(const bf16x8*)&Ksm[buf][(n * 16 + cl) * 64 + ((gp + cl + 4) & 7) * 8];
      z = MFMA(q0, kf0, z);
      z = MFMA(q1, kf1, z);
      sfr[n] = z;
    }
    __builtin_amdgcn_s_setprio(0);

    bool diag = (t == qb);
    #pragma unroll
    for (int n = 0; n < 4; ++n)
      #pragma unroll
      for (int j = 0; j < 4; ++j) {
        float sv = sfr[n][j] * 0.03125f;
        if (diag) {
          int lr = wave * 16 + gp * 4 + j;
          int lc = n * 16 + cl;
          sv = (lc <= lr) ? sv : -1e30f;
        }
        sfr[n][j] = sv;
      }
    float so[4];
    #pragma unroll
    for (int j = 0; j < 4; ++j) {
      float tm = fmaxf(fmaxf(sfr[0][j], sfr[1][j]), fmaxf(sfr[2][j], sfr[3][j]));
      tm = fmaxf(tm, __shfl_xor(tm, 1));
      tm = fmaxf(tm, __shfl_xor(tm, 2));
      tm = fmaxf(tm, __shfl_xor(tm, 4));
      tm = fmaxf(tm, __shfl_xor(tm, 8));
      float mn = fmaxf(mrow[j], tm);
      so[j] = __expf(mrow[j] - mn);
      mrow[j] = mn;
      float ts = 0.f;
      #pragma unroll
      for (int n = 0; n < 4; ++n) {
        float p = __expf(sfr[n][j] - mn);
        sfr[n][j] = p;
        ts += p;
      }
      ts += __shfl_xor(ts, 1); ts += __shfl_xor(ts, 2);
      ts += __shfl_xor(ts, 4); ts += __shfl_xor(ts, 8);
      lrow[j] = lrow[j] * so[j] + ts;
    }
    #pragma unroll
    for (int n = 0; n < 4; ++n)
      #pragma unroll
      for (int j = 0; j < 4; ++j)
        oacc[n][j] *= so[j];

    #pragma unroll
    for (int n = 0; n < 4; ++n)
      #pragma unroll
      for (int j = 0; j < 4; ++j)
        Psm[(wave * 16 + gp * 4 + j) * LSTR + n * 16 + cl] = f2bf(sfr[n][j]);
    __builtin_amdgcn_sched_barrier(0);

    bf16x8 pa0 = *(const bf16x8*)&Psm[(wave * 16 + cl) * LSTR + gp * 8];
    bf16x8 pa1 = *(const bf16x8*)&Psm[(wave * 16 + cl) * LSTR + 32 + gp * 8];
    __builtin_amdgcn_s_setprio(1);
    #pragma unroll
    for (int n = 0; n < 4; ++n) {
      bf16x8 vb0 = *(const bf16x8*)&Vsm[buf][(n * 16 + cl) * LSTR + gp * 8];
      bf16x8 vb1 = *(const bf16x8*)&Vsm[buf][(n * 16 + cl) * LSTR + 32 + gp * 8];
      oacc[n] = MFMA(pa0, vb0, oacc[n]);
      oacc[n] = MFMA(pa1, vb1, oacc[n]);
    }
    __builtin_amdgcn_s_setprio(0);
  };

  stageK(0, 0);
  loadV(0);
  writeV(0);
  __syncthreads();

  for (int t = 0; t <= qbB; ++t) {
    int buf = t & 1;
    bool more = t < qbB;
    if (more) { stageK(t + 1, buf ^ 1); loadV(t + 1); }

    stateStep(t, buf, qbB, qB0, qB1, mB, lB, oB);
    if (more) writeV(buf ^ 1);
    if (t <= qbA)
      stateStep(t, buf, qbA, qA0, qA1, mA, lA, oA);

    __syncthreads();
  }

  #pragma unroll
  for (int n = 0; n < 4; ++n)
    #pragma unroll
    for (int j = 0; j < 4; ++j) {
      int lr = wave * 16 + gp * 4 + j;
      int d = n * 16 + cl;
      outb[(size_t)(b * SEQLEN + qbA * 64 + lr) * HIDDEN + h * HDIM + d] = f2bf(oA[n][j] / lA[j]);
      outb[(size_t)(b * SEQLEN + qbB * 64 + lr) * HIDDEN + h * HDIM + d] = f2bf(oB[n][j] / lB[j]);
    }
}

extern "C" void kernel_launch(void* const* d_in, const int* in_sizes, int n_in,
                              void* d_out, int out_size, void* d_ws, size_t ws_size,
                              hipStream_t stream) {
  const int*   ids    = (const int*)d_in[0];
  const float* W_word = (const float*)d_in[1];
  const float* W_pos  = (const float*)d_in[2];
  const float* Wq     = (const float*)d_in[3];
  const float* Wk     = (const float*)d_in[4];
  const float* Wv     = (const float*)d_in[5];
  const float* Wo     = (const float*)d_in[6];
  const float* W1     = (const float*)d_in[7];
  const float* W2     = (const float*)d_in[8];
  const float* W_eh   = (const float*)d_in[9];
  const float* W_he   = (const float*)d_in[10];
  const float* W_lm   = (const float*)d_in[11];
  float* out = (float*)d_out;
  char*  ob  = (char*)d_out;
  char*  wb  = (char*)d_ws;

  const size_t MB = 1024 * 1024;
  u16*   h0b   = (u16*)(ob + 32 * MB);
  u16*   h1b   = (u16*)(ob + 36 * MB);
  u16*   qkvb  = (u16*)(ob + 44 * MB);
  u16*   attnb = (u16*)(ob + 68 * MB);
  u16*   h2b   = (u16*)(ob + 76 * MB);
  u16*   xb    = (u16*)(ob + 84 * MB);
  u16*   h3b   = (u16*)(ob + 116 * MB);
  u16*   Wqkv_b= (u16*)(ob + 124 * MB);
  u16*   Wo_b  = (u16*)(ob + 130 * MB);
  u16*   W1_b  = (u16*)(ob + 132 * MB);
  u16*   W2_b  = (u16*)(ob + 140 * MB);
  u16*   Weh_b = (u16*)(ob + 148 * MB);
  u16*   Whe_b = (u16*)(ob + 149 * MB);
  u16*   he_b  = (u16*)(wb + 0);
  u16*   Wlm_b = (u16*)(wb + 4 * MB);
  bool big_ws = ws_size >= 36 * MB;

  Prep pp;
  pp.src[0] = Wq;  pp.dst[0] = Wqkv_b + 0 * 1024 * 1024;
  pp.src[1] = Wk;  pp.dst[1] = Wqkv_b + 1 * 1024 * 1024;
  pp.src[2] = Wv;  pp.dst[2] = Wqkv_b + 2 * 1024 * 1024;
  pp.src[3] = Wo;  pp.dst[3] = Wo_b;
  pp.src[4] = W1;  pp.dst[4] = W1_b;
  pp.src[5] = W2;  pp.dst[5] = W2_b;
  pp.src[6] = W_eh; pp.dst[6] = Weh_b;
  pp.src[7] = W_he; pp.dst[7] = Whe_b;
  pp.wlm = W_lm; pp.wlm_dst = big_ws ? Wlm_b : nullptr;
  pp.ids = ids; pp.wword = W_word; pp.wpos = W_pos; pp.h0b = h0b;
  prep_kernel<<<dim3(31360), 256, 0, stream>>>(pp);

  // h1b = h0 @ W_eh.T            (BN=64: 512 blocks, 2/CU)
  gemm128<0, false, true, false, false, false, 64><<<dim3(32, 16), 256, 0, stream>>>(
      h0b, Weh_b, nullptr, nullptr, h1b, nullptr, 512, HIDDEN);
  // qkv = h1 @ Wqkv.T            (BN=128: 768 blocks)
  gemm128<0, false, true, false, false, false, 128><<<dim3(32, 24), 256, 0, stream>>>(
      h1b, Wqkv_b, nullptr, nullptr, qkvb, nullptr, 1024, 3 * HIDDEN);
  // attention (paired q-blocks)
  attn_kernel<<<dim3(8, 16, 4), 256, 0, stream>>>(qkvb, attnb);
  // h2b = h1b + attn @ Wo.T      (BN=64: 512 blocks, 2/CU)
  gemm128<1, false, true, false, false, false, 64><<<dim3(32, 16), 256, 0, stream>>>(
      attnb, Wo_b, nullptr, nullptr, h2b, h1b, 1024, HIDDEN);
  // x = relu(h2 @ W1.T)          (256^2, round-10 dual-barrier)
  gemm256<2, false, true, false><<<dim3(16, 16), 512, 0, stream>>>(
      h2b, W1_b, nullptr, xb, nullptr, 1024, 4 * HIDDEN);
  // h3b = h2b + x @ W2.T         (BN=64: 512 blocks, 2/CU, K=4096)
  gemm128<1, false, true, false, false, false, 64><<<dim3(32, 16), 256, 0, stream>>>(
      xb, W2_b, nullptr, nullptr, h3b, h2b, 4096, HIDDEN);
  // he = h3 @ W_he.T             (BN=64: 256 blocks)
  gemm128<0, false, true, false, false, false, 64><<<dim3(32, 8), 256, 0, stream>>>(
      h3b, Whe_b, nullptr, nullptr, he_b, nullptr, 1024, EMBED);
  // logits = he @ W_lm.T         (256^2, coalesced NT epilogue)
  if (big_ws)
    gemm256<0, true, false, true, true><<<dim3(16, 125), 512, 0, stream>>>(
        he_b, Wlm_b, out, nullptr, nullptr, 512, VOCAB);
  else
    gemm128<0, true, false, true, true, true, 128><<<dim3(32, 250), 256, 0, stream>>>(
        he_b, nullptr, W_lm, out, nullptr, nullptr, 512, VOCAB);
}